// Round 2
// baseline (647.445 us; speedup 1.0000x reference)
//
#include <hip/hip_runtime.h>
#include <cfloat>
#include <cmath>

// GAT layer: B=4,S=256,N=257,E=256, IN=OUT=128, EDIM=16, all f32.
// Phases:
//   K0 detect+canon: edge_mask dtype sniffing (int32 vs uint8) -> uint8 in ws
//   K1 gemm:   h = x @ W            (h stored in d_out as scratch — fully
//                                    overwritten by K3, per-block read-before-write)
//   K2 alpha:  per-(b,s) logits + softmax -> alpha in d_ws
//   K3 agg:    per-(b,s, D/4) LDS scatter-accumulate + ELU -> d_out
// Index semantics replicate JAX: gather for logits zeroes idx<0; aggregation
// uses where(mask, idx, 0) then NEGATIVE WRAP (-1 -> N-1=256) for both the
// gather and the scatter (take_along_axis/.at[].add normalize negatives).

#define BB 4
#define SS 256
#define NNODE 257
#define EE 256
#define DIN 128
#define DOUT 128
#define EDIMC 16
#define NMASK (BB * SS * EE)   // 262144

// ws layout (bytes):
//   [0, 4)              : mask-layout flag (1 = byte layout, 0 = int32 layout)
//   [1024, 1024+262144) : canonical uint8 edge mask
//   [266240, +1 MiB)    : alpha [B,S,E] f32
#define WS_FLAG_OFF  0
#define WS_MASK_OFF  1024
#define WS_ALPHA_OFF 266240

// ------------------------------------------------------- mask dtype sniffing
// If the harness pushed bool as int32, the first 256 words are all 0/1.
// If it pushed raw bytes, ~90% density makes some word > 1 with certainty.
__global__ void detect_mask_kernel(const unsigned int* __restrict__ m, int* flag) {
    unsigned int v = 0;
    for (int i = threadIdx.x; i < 256; i += 64) v |= m[i];
    int bad = (v > 1u) ? 1 : 0;
    bad = __any(bad) ? 1 : 0;
    if (threadIdx.x == 0) *flag = bad;
}

__global__ __launch_bounds__(256) void mask_canon_kernel(
        const int* __restrict__ m32, const unsigned char* __restrict__ m8,
        const int* __restrict__ flag, unsigned char* __restrict__ out) {
    const bool byteLayout = (*flag != 0);
    int i = blockIdx.x * 256 + threadIdx.x;
    if (i < NMASK) out[i] = byteLayout ? (m8[i] != 0) : (m32[i] != 0);
}

// ---------------------------------------------------------------- GEMM
// h[M,128] = x[M,128] @ W[128,128], M = B*S*N = 263168 = 2056 * 128
__global__ __launch_bounds__(256) void gemm_kernel(const float* __restrict__ x,
                                                   const float* __restrict__ W,
                                                   float* __restrict__ h) {
    __shared__ float xs[32][132];   // [k][m], padded
    __shared__ float wsh[32][132];  // [k][n], padded
    const int tid = threadIdx.x;
    const long m0 = (long)blockIdx.x * 128;
    const int tm = tid >> 4;        // 0..15
    const int tn = tid & 15;        // 0..15
    const int mr = tm * 8, nr = tn * 8;
    float acc[8][8];
#pragma unroll
    for (int i = 0; i < 8; ++i)
#pragma unroll
        for (int j = 0; j < 8; ++j) acc[i][j] = 0.f;

    for (int kt = 0; kt < 4; ++kt) {
#pragma unroll
        for (int j = 0; j < 4; ++j) {
            int idx = j * 256 + tid;      // 0..1023
            int row = idx >> 3;           // 0..127
            int kq  = idx & 7;            // 0..7
            float4 v = *reinterpret_cast<const float4*>(
                x + (m0 + row) * DIN + kt * 32 + kq * 4);
            xs[kq * 4 + 0][row] = v.x;
            xs[kq * 4 + 1][row] = v.y;
            xs[kq * 4 + 2][row] = v.z;
            xs[kq * 4 + 3][row] = v.w;
        }
#pragma unroll
        for (int j = 0; j < 4; ++j) {
            int idx = j * 256 + tid;
            int row = idx >> 5;           // k 0..31
            int nq  = idx & 31;           // 0..31
            float4 v = *reinterpret_cast<const float4*>(
                W + (kt * 32 + row) * DOUT + nq * 4);
            *reinterpret_cast<float4*>(&wsh[row][nq * 4]) = v;
        }
        __syncthreads();
#pragma unroll
        for (int k = 0; k < 32; ++k) {
            float4 a0 = *reinterpret_cast<const float4*>(&xs[k][mr]);
            float4 a1 = *reinterpret_cast<const float4*>(&xs[k][mr + 4]);
            float4 b0 = *reinterpret_cast<const float4*>(&wsh[k][nr]);
            float4 b1 = *reinterpret_cast<const float4*>(&wsh[k][nr + 4]);
            float av[8] = {a0.x, a0.y, a0.z, a0.w, a1.x, a1.y, a1.z, a1.w};
            float bv[8] = {b0.x, b0.y, b0.z, b0.w, b1.x, b1.y, b1.z, b1.w};
#pragma unroll
            for (int i = 0; i < 8; ++i)
#pragma unroll
                for (int jj = 0; jj < 8; ++jj)
                    acc[i][jj] = fmaf(av[i], bv[jj], acc[i][jj]);
        }
        __syncthreads();
    }
#pragma unroll
    for (int i = 0; i < 8; ++i) {
        float* dst = h + (m0 + mr + i) * DOUT + nr;
        *reinterpret_cast<float4*>(dst) =
            make_float4(acc[i][0], acc[i][1], acc[i][2], acc[i][3]);
        *reinterpret_cast<float4*>(dst + 4) =
            make_float4(acc[i][4], acc[i][5], acc[i][6], acc[i][7]);
    }
}

// ---------------------------------------------------------------- alpha
// one block per (b,s): node dots -> edge logits -> masked softmax
__global__ __launch_bounds__(256) void alpha_kernel(
        const float* __restrict__ h, const int* __restrict__ eidx,
        const float* __restrict__ eattr, const unsigned char* __restrict__ emask,
        const float* __restrict__ a, float* __restrict__ alpha_out) {
    __shared__ float pq[NNODE], pt[NNODE];
    __shared__ float ae[EDIMC];
    __shared__ float red[4];
    __shared__ int redi[4];
    const int tid = threadIdx.x;
    const int bs = blockIdx.x;
    const int lane = tid & 63, wave = tid >> 6;
    if (tid < EDIMC) ae[tid] = a[2 * DOUT + tid];
    const float a0 = a[lane], a1 = a[lane + 64];
    const float a2 = a[128 + lane], a3 = a[192 + lane];
    const float* hb = h + (long)bs * NNODE * DIN;
    for (int n = wave; n < NNODE; n += 4) {
        const float* hr = hb + n * DIN;
        float v0 = hr[lane], v1 = hr[lane + 64];
        float s = v0 * a0 + v1 * a1;
        float t = v0 * a2 + v1 * a3;
#pragma unroll
        for (int o = 32; o > 0; o >>= 1) {
            s += __shfl_xor(s, o);
            t += __shfl_xor(t, o);
        }
        if (lane == 0) { pq[n] = s; pt[n] = t; }
    }
    __syncthreads();

    const int e = tid;                       // E == 256 == blockDim
    const long ebase = (long)bs * EE + e;
    const int si = eidx[2 * ebase];
    const int ti = eidx[2 * ebase + 1];
    const float4* ea4 = reinterpret_cast<const float4*>(eattr + ebase * EDIMC);
    float dea = 0.f;
#pragma unroll
    for (int j = 0; j < 4; ++j) {
        float4 u = ea4[j];
        dea += u.x * ae[4 * j] + u.y * ae[4 * j + 1] +
               u.z * ae[4 * j + 2] + u.w * ae[4 * j + 3];
    }
    float val = (si >= 0 ? pq[si] : 0.f) + (ti >= 0 ? pt[ti] : 0.f) + dea;
    val = val > 0.f ? val : 0.2f * val;      // leaky_relu(0.2)
    const bool m = emask[ebase] != 0;

    float lg = m ? val : -FLT_MAX;
    float wm = lg;
    int anyv = m ? 1 : 0;
#pragma unroll
    for (int o = 32; o > 0; o >>= 1) {
        wm = fmaxf(wm, __shfl_xor(wm, o));
        anyv |= __shfl_xor(anyv, o);
    }
    if (lane == 0) { red[wave] = wm; redi[wave] = anyv; }
    __syncthreads();
    const float gmax = fmaxf(fmaxf(red[0], red[1]), fmaxf(red[2], red[3]));
    const int ganyv = redi[0] | redi[1] | redi[2] | redi[3];
    float ex = m ? expf(val - gmax) : 0.f;
    float sm = ex;
#pragma unroll
    for (int o = 32; o > 0; o >>= 1) sm += __shfl_xor(sm, o);
    __syncthreads();
    if (lane == 0) red[wave] = sm;
    __syncthreads();
    const float gsum = red[0] + red[1] + red[2] + red[3];
    alpha_out[ebase] = ganyv ? ex / gsum : (1.0f / EE);
}

// ---------------------------------------------------------------- aggregate
// grid (B*S, 4): each block owns one (b,s) and 32 of the 128 feature dims.
__global__ __launch_bounds__(256) void agg_kernel(
        const float* __restrict__ h, const int* __restrict__ eidx,
        const unsigned char* __restrict__ emask, const float* __restrict__ alpha,
        float* __restrict__ out) {
    __shared__ float agg[NNODE * 32];        // 32,896 B
    const int tid = threadIdx.x;
    const int bs = blockIdx.x;
    const int dbase = blockIdx.y * 32;
    const int slot = tid >> 5, d = tid & 31;
    for (int i = tid; i < NNODE * 32; i += 256) agg[i] = 0.f;
    __syncthreads();

    const float* hb = h + (long)bs * NNODE * DIN + dbase;
    const long eb0 = (long)bs * EE;
    for (int e0 = 0; e0 < EE; e0 += 8) {
        const int e = e0 + slot;
        const float al = alpha[eb0 + e];
        if (al != 0.f) {                     // zero-alpha edges contribute 0
            const int si = eidx[2 * (eb0 + e)];
            const int ti = eidx[2 * (eb0 + e) + 1];
            const bool m = emask[eb0 + e] != 0;
            int vs = m ? si : 0; if (vs < 0) vs += NNODE;   // JAX negative wrap
            int vt = m ? ti : 0; if (vt < 0) vt += NNODE;
            const float hs = hb[(long)vs * DIN + d];
            const float ht = hb[(long)vt * DIN + d];
            atomicAdd(&agg[vt * 32 + d], al * hs);
            atomicAdd(&agg[vs * 32 + d], al * ht);
        }
    }
    __syncthreads();

    float* ob = out + (long)bs * NNODE * DIN + dbase;
    for (int n = slot; n < NNODE; n += 8) {
        const float v = agg[n * 32 + d];
        ob[(long)n * DIN + d] = v > 0.f ? v : expm1f(v);   // elu
    }
}

// ---------------------------------------------------------------- launch
extern "C" void kernel_launch(void* const* d_in, const int* in_sizes, int n_in,
                              void* d_out, int out_size, void* d_ws, size_t ws_size,
                              hipStream_t stream) {
    const float* x     = (const float*)d_in[0];
    const int* eidx    = (const int*)d_in[1];
    const float* eattr = (const float*)d_in[2];
    /* d_in[3] node_mask: unused by the reference forward */
    const void* emraw  = d_in[4];
    const float* W     = (const float*)d_in[5];
    const float* a     = (const float*)d_in[6];
    float* out = (float*)d_out;

    char* ws = (char*)d_ws;
    int* flag            = (int*)(ws + WS_FLAG_OFF);
    unsigned char* mask8 = (unsigned char*)(ws + WS_MASK_OFF);
    float* alpha         = (float*)(ws + WS_ALPHA_OFF);
    float* h             = out;   // scratch aliasing the output buffer

    detect_mask_kernel<<<1, 64, 0, stream>>>((const unsigned int*)emraw, flag);
    mask_canon_kernel<<<NMASK / 256, 256, 0, stream>>>(
        (const int*)emraw, (const unsigned char*)emraw, flag, mask8);

    const int M_BLOCKS = (BB * SS * NNODE) / 128;        // 2056
    gemm_kernel<<<M_BLOCKS, 256, 0, stream>>>(x, W, h);
    alpha_kernel<<<BB * SS, 256, 0, stream>>>(h, eidx, eattr, mask8, a, alpha);
    agg_kernel<<<dim3(BB * SS, 4), 256, 0, stream>>>(h, eidx, mask8, alpha, out);
}

// Round 5
// 626.852 us; speedup vs baseline: 1.0329x; 1.0329x over previous
//
#include <hip/hip_runtime.h>
#include <cfloat>
#include <cmath>

// GAT layer: B=4,S=256,N=257,E=256, IN=OUT=128, EDIM=16, all f32.
// Phases:
//   K0 detect+canon: edge_mask dtype sniffing (int32 vs uint8) -> uint8 in ws
//   K1 gemm:   h = x @ W, epilogue also emits pq = h·a[0:128], pt = h·a[128:256]
//              (h stored in d_out as scratch — fully overwritten by K3)
//   K2 alpha2: per-(b,s) edge logits from pq/pt gathers + masked softmax -> ws
//   K3 agg:    per-(b,s, D/8) LDS-staged scatter-accumulate + ELU -> d_out
//              (edge loop is LDS-only: h slice + edge metadata staged first)
// Index semantics replicate JAX: gather for logits zeroes idx<0; aggregation
// uses where(mask, idx, 0) then NEGATIVE WRAP (-1 -> N-1=256) for both the
// gather and the scatter (take_along_axis/.at[].add normalize negatives).

#define BB 4
#define SS 256
#define NNODE 257
#define EE 256
#define DIN 128
#define DOUT 128
#define EDIMC 16
#define NMASK (BB * SS * EE)          // 262144
#define MROWS (BB * SS * NNODE)       // 263168

// ws layout (bytes):
#define WS_FLAG_OFF  0
#define WS_MASK_OFF  1024
#define WS_ALPHA_OFF 266240                       // + NMASK*4   = 1 MiB
#define WS_PQ_OFF    (WS_ALPHA_OFF + NMASK * 4)   // + MROWS*4
#define WS_PT_OFF    (WS_PQ_OFF + MROWS * 4)
#define WS_NEEDED    (WS_PT_OFF + MROWS * 4)      // ~3.3 MB

// ------------------------------------------------------- mask dtype sniffing
__global__ void detect_mask_kernel(const unsigned int* __restrict__ m, int* flag) {
    unsigned int v = 0;
    for (int i = threadIdx.x; i < 256; i += 64) v |= m[i];
    int bad = (v > 1u) ? 1 : 0;
    bad = __any(bad) ? 1 : 0;
    if (threadIdx.x == 0) *flag = bad;
}

__global__ __launch_bounds__(256) void mask_canon_kernel(
        const int* __restrict__ m32, const unsigned char* __restrict__ m8,
        const int* __restrict__ flag, unsigned char* __restrict__ out) {
    const bool byteLayout = (*flag != 0);
    int i = blockIdx.x * 256 + threadIdx.x;
    if (i < NMASK) out[i] = byteLayout ? (m8[i] != 0) : (m32[i] != 0);
}

// ---------------------------------------------------------------- GEMM
// h[M,128] = x[M,128] @ W[128,128], M = 263168 = 2056*128.
// Epilogue: per-row dots with attention vector halves -> pq/pt (if non-null).
__global__ __launch_bounds__(256) void gemm_kernel(const float* __restrict__ x,
                                                   const float* __restrict__ W,
                                                   const float* __restrict__ a,
                                                   float* __restrict__ h,
                                                   float* __restrict__ pq,
                                                   float* __restrict__ pt) {
    __shared__ float xs[32][132];   // [k][m], padded
    __shared__ float wsh[32][132];  // [k][n], padded
    const int tid = threadIdx.x;
    const long m0 = (long)blockIdx.x * 128;
    const int tm = tid >> 4;        // 0..15
    const int tn = tid & 15;        // 0..15
    const int mr = tm * 8, nr = tn * 8;
    float acc[8][8];
#pragma unroll
    for (int i = 0; i < 8; ++i)
#pragma unroll
        for (int j = 0; j < 8; ++j) acc[i][j] = 0.f;

    for (int kt = 0; kt < 4; ++kt) {
#pragma unroll
        for (int j = 0; j < 4; ++j) {
            int idx = j * 256 + tid;      // 0..1023
            int row = idx >> 3;           // 0..127
            int kq  = idx & 7;            // 0..7
            float4 v = *reinterpret_cast<const float4*>(
                x + (m0 + row) * DIN + kt * 32 + kq * 4);
            xs[kq * 4 + 0][row] = v.x;
            xs[kq * 4 + 1][row] = v.y;
            xs[kq * 4 + 2][row] = v.z;
            xs[kq * 4 + 3][row] = v.w;
        }
#pragma unroll
        for (int j = 0; j < 4; ++j) {
            int idx = j * 256 + tid;
            int row = idx >> 5;           // k 0..31
            int nq  = idx & 31;           // 0..31
            float4 v = *reinterpret_cast<const float4*>(
                W + (kt * 32 + row) * DOUT + nq * 4);
            *reinterpret_cast<float4*>(&wsh[row][nq * 4]) = v;
        }
        __syncthreads();
#pragma unroll
        for (int k = 0; k < 32; ++k) {
            float4 a0 = *reinterpret_cast<const float4*>(&xs[k][mr]);
            float4 a1 = *reinterpret_cast<const float4*>(&xs[k][mr + 4]);
            float4 b0 = *reinterpret_cast<const float4*>(&wsh[k][nr]);
            float4 b1 = *reinterpret_cast<const float4*>(&wsh[k][nr + 4]);
            float av[8] = {a0.x, a0.y, a0.z, a0.w, a1.x, a1.y, a1.z, a1.w};
            float bv[8] = {b0.x, b0.y, b0.z, b0.w, b1.x, b1.y, b1.z, b1.w};
#pragma unroll
            for (int i = 0; i < 8; ++i)
#pragma unroll
                for (int jj = 0; jj < 8; ++jj)
                    acc[i][jj] = fmaf(av[i], bv[jj], acc[i][jj]);
        }
        __syncthreads();
    }
#pragma unroll
    for (int i = 0; i < 8; ++i) {
        float* dst = h + (m0 + mr + i) * DOUT + nr;
        *reinterpret_cast<float4*>(dst) =
            make_float4(acc[i][0], acc[i][1], acc[i][2], acc[i][3]);
        *reinterpret_cast<float4*>(dst + 4) =
            make_float4(acc[i][4], acc[i][5], acc[i][6], acc[i][7]);
    }

    if (pq != nullptr) {
        // per-row attention dots: reduce acc[i][:] * a[nr..nr+7] across the
        // 16-lane tn-group that shares the row (tid = tm*16+tn, tn contiguous).
        float aq[8], at_[8];
#pragma unroll
        for (int j = 0; j < 8; ++j) {
            aq[j]  = a[nr + j];
            at_[j] = a[DOUT + nr + j];
        }
#pragma unroll
        for (int i = 0; i < 8; ++i) {
            float s = 0.f, t = 0.f;
#pragma unroll
            for (int j = 0; j < 8; ++j) {
                s = fmaf(acc[i][j], aq[j], s);
                t = fmaf(acc[i][j], at_[j], t);
            }
#pragma unroll
            for (int o = 1; o < 16; o <<= 1) {
                s += __shfl_xor(s, o);
                t += __shfl_xor(t, o);
            }
            if (tn == 0) {
                pq[m0 + mr + i] = s;
                pt[m0 + mr + i] = t;
            }
        }
    }
}

// ---------------------------------------------------------------- alpha2
// one block per (b,s): edge logits from pq/pt gathers + masked softmax
__global__ __launch_bounds__(256) void alpha2_kernel(
        const float* __restrict__ pq, const float* __restrict__ pt,
        const int* __restrict__ eidx, const float* __restrict__ eattr,
        const unsigned char* __restrict__ emask, const float* __restrict__ a,
        float* __restrict__ alpha_out) {
    __shared__ float ae[EDIMC];
    __shared__ float red[4];
    __shared__ int redi[4];
    const int tid = threadIdx.x;
    const int bs = blockIdx.x;
    const int lane = tid & 63, wave = tid >> 6;
    if (tid < EDIMC) ae[tid] = a[2 * DOUT + tid];
    __syncthreads();

    const long ebase = (long)bs * EE + tid;
    const int si = eidx[2 * ebase];
    const int ti = eidx[2 * ebase + 1];
    const float4* ea4 = reinterpret_cast<const float4*>(eattr + ebase * EDIMC);
    float dea = 0.f;
#pragma unroll
    for (int j = 0; j < 4; ++j) {
        float4 u = ea4[j];
        dea += u.x * ae[4 * j] + u.y * ae[4 * j + 1] +
               u.z * ae[4 * j + 2] + u.w * ae[4 * j + 3];
    }
    const long nb = (long)bs * NNODE;
    float val = (si >= 0 ? pq[nb + si] : 0.f) + (ti >= 0 ? pt[nb + ti] : 0.f) + dea;
    val = val > 0.f ? val : 0.2f * val;      // leaky_relu(0.2)
    const bool m = emask[ebase] != 0;

    float lg = m ? val : -FLT_MAX;
    float wm = lg;
    int anyv = m ? 1 : 0;
#pragma unroll
    for (int o = 32; o > 0; o >>= 1) {
        wm = fmaxf(wm, __shfl_xor(wm, o));
        anyv |= __shfl_xor(anyv, o);
    }
    if (lane == 0) { red[wave] = wm; redi[wave] = anyv; }
    __syncthreads();
    const float gmax = fmaxf(fmaxf(red[0], red[1]), fmaxf(red[2], red[3]));
    const int ganyv = redi[0] | redi[1] | redi[2] | redi[3];
    float ex = m ? expf(val - gmax) : 0.f;
    float sm = ex;
#pragma unroll
    for (int o = 32; o > 0; o >>= 1) sm += __shfl_xor(sm, o);
    __syncthreads();
    if (lane == 0) red[wave] = sm;
    __syncthreads();
    const float gsum = red[0] + red[1] + red[2] + red[3];
    alpha_out[ebase] = ganyv ? ex / gsum : (1.0f / EE);
}

// ------------------------------------------- alpha (fallback, reads h)
__global__ __launch_bounds__(256) void alpha_kernel(
        const float* __restrict__ h, const int* __restrict__ eidx,
        const float* __restrict__ eattr, const unsigned char* __restrict__ emask,
        const float* __restrict__ a, float* __restrict__ alpha_out) {
    __shared__ float pq[NNODE], pt[NNODE];
    __shared__ float ae[EDIMC];
    __shared__ float red[4];
    __shared__ int redi[4];
    const int tid = threadIdx.x;
    const int bs = blockIdx.x;
    const int lane = tid & 63, wave = tid >> 6;
    if (tid < EDIMC) ae[tid] = a[2 * DOUT + tid];
    const float a0 = a[lane], a1 = a[lane + 64];
    const float a2 = a[128 + lane], a3 = a[192 + lane];
    const float* hb = h + (long)bs * NNODE * DIN;
    for (int n = wave; n < NNODE; n += 4) {
        const float* hr = hb + n * DIN;
        float v0 = hr[lane], v1 = hr[lane + 64];
        float s = v0 * a0 + v1 * a1;
        float t = v0 * a2 + v1 * a3;
#pragma unroll
        for (int o = 32; o > 0; o >>= 1) {
            s += __shfl_xor(s, o);
            t += __shfl_xor(t, o);
        }
        if (lane == 0) { pq[n] = s; pt[n] = t; }
    }
    __syncthreads();

    const long ebase = (long)bs * EE + tid;
    const int si = eidx[2 * ebase];
    const int ti = eidx[2 * ebase + 1];
    const float4* ea4 = reinterpret_cast<const float4*>(eattr + ebase * EDIMC);
    float dea = 0.f;
#pragma unroll
    for (int j = 0; j < 4; ++j) {
        float4 u = ea4[j];
        dea += u.x * ae[4 * j] + u.y * ae[4 * j + 1] +
               u.z * ae[4 * j + 2] + u.w * ae[4 * j + 3];
    }
    float val = (si >= 0 ? pq[si] : 0.f) + (ti >= 0 ? pt[ti] : 0.f) + dea;
    val = val > 0.f ? val : 0.2f * val;
    const bool m = emask[ebase] != 0;

    float lg = m ? val : -FLT_MAX;
    float wm = lg;
    int anyv = m ? 1 : 0;
#pragma unroll
    for (int o = 32; o > 0; o >>= 1) {
        wm = fmaxf(wm, __shfl_xor(wm, o));
        anyv |= __shfl_xor(anyv, o);
    }
    if (lane == 0) { red[wave] = wm; redi[wave] = anyv; }
    __syncthreads();
    const float gmax = fmaxf(fmaxf(red[0], red[1]), fmaxf(red[2], red[3]));
    const int ganyv = redi[0] | redi[1] | redi[2] | redi[3];
    float ex = m ? expf(val - gmax) : 0.f;
    float sm = ex;
#pragma unroll
    for (int o = 32; o > 0; o >>= 1) sm += __shfl_xor(sm, o);
    __syncthreads();
    if (lane == 0) red[wave] = sm;
    __syncthreads();
    const float gsum = red[0] + red[1] + red[2] + red[3];
    alpha_out[ebase] = ganyv ? ex / gsum : (1.0f / EE);
}

// ---------------------------------------------------------------- aggregate
// grid (B*S, 8): each block owns one (b,s) and 16 of the 128 feature dims.
// Edge loop is LDS-only: h-slice + metadata staged, acc in LDS, then ELU out.
#define DSL 16                    // dims per block
#define PAD 17                    // padded row stride (bank spread)
__global__ __launch_bounds__(256) void agg_kernel(
        const float* __restrict__ h, const int* __restrict__ eidx,
        const unsigned char* __restrict__ emask, const float* __restrict__ alpha,
        float* __restrict__ out) {
    __shared__ float hs[NNODE * PAD];     // 17,476 B
    __shared__ float acc[NNODE * PAD];    // 17,476 B
    __shared__ float meta_a[EE];          // 1 KB
    __shared__ int   meta_v[EE];          // 1 KB (vs | vt<<16)
    const int tid = threadIdx.x;
    const int bs = blockIdx.x;
    const int dbase = blockIdx.y * DSL;
    const int slot = tid >> 4, d = tid & 15;   // 16 slots x 16 dims

    const float* hb = h + (long)bs * NNODE * DIN + dbase;

    // stage h slice: 257 rows x 4 float4 chunks = 1028 vector loads
    for (int i = tid; i < NNODE * 4; i += 256) {
        int row = i >> 2, q = i & 3;
        float4 v = *reinterpret_cast<const float4*>(hb + (long)row * DIN + q * 4);
        float* dst = &hs[row * PAD + q * 4];
        dst[0] = v.x; dst[1] = v.y; dst[2] = v.z; dst[3] = v.w;
    }
    for (int i = tid; i < NNODE * PAD; i += 256) acc[i] = 0.f;
    {
        const long eb = (long)bs * EE + tid;
        const int si = eidx[2 * eb];
        const int ti = eidx[2 * eb + 1];
        const bool m = emask[eb] != 0;
        int vs = m ? si : 0; if (vs < 0) vs += NNODE;   // JAX negative wrap
        int vt = m ? ti : 0; if (vt < 0) vt += NNODE;
        meta_a[tid] = alpha[eb];
        meta_v[tid] = vs | (vt << 16);
    }
    __syncthreads();

    // LDS-only edge loop: 16 iterations, 16 lanes per edge
#pragma unroll 4
    for (int e0 = 0; e0 < EE; e0 += 16) {
        const int e = e0 + slot;
        const float al = meta_a[e];
        if (al != 0.f) {
            const int pv = meta_v[e];
            const int vs = pv & 0xffff, vt = pv >> 16;
            const float hsv = hs[vs * PAD + d];
            const float htv = hs[vt * PAD + d];
            atomicAdd(&acc[vt * PAD + d], al * hsv);
            atomicAdd(&acc[vs * PAD + d], al * htv);
        }
    }
    __syncthreads();

    float* ob = out + (long)bs * NNODE * DIN + dbase;
    for (int n = slot; n < NNODE; n += 16) {
        const float v = acc[n * PAD + d];
        ob[(long)n * DIN + d] = v > 0.f ? v : expm1f(v);   // elu
    }
}

// ---------------------------------------------------------------- launch
extern "C" void kernel_launch(void* const* d_in, const int* in_sizes, int n_in,
                              void* d_out, int out_size, void* d_ws, size_t ws_size,
                              hipStream_t stream) {
    const float* x     = (const float*)d_in[0];
    const int* eidx    = (const int*)d_in[1];
    const float* eattr = (const float*)d_in[2];
    /* d_in[3] node_mask: unused by the reference forward */
    const void* emraw  = d_in[4];
    const float* W     = (const float*)d_in[5];
    const float* a     = (const float*)d_in[6];
    float* out = (float*)d_out;

    char* ws = (char*)d_ws;
    int* flag            = (int*)(ws + WS_FLAG_OFF);
    unsigned char* mask8 = (unsigned char*)(ws + WS_MASK_OFF);
    float* alpha         = (float*)(ws + WS_ALPHA_OFF);
    float* h             = out;   // scratch aliasing the output buffer
    const bool fused     = (ws_size >= (size_t)WS_NEEDED);
    float* pq            = fused ? (float*)(ws + WS_PQ_OFF) : nullptr;
    float* pt            = fused ? (float*)(ws + WS_PT_OFF) : nullptr;

    detect_mask_kernel<<<1, 64, 0, stream>>>((const unsigned int*)emraw, flag);
    mask_canon_kernel<<<NMASK / 256, 256, 0, stream>>>(
        (const int*)emraw, (const unsigned char*)emraw, flag, mask8);

    const int M_BLOCKS = MROWS / 128;        // 2056
    gemm_kernel<<<M_BLOCKS, 256, 0, stream>>>(x, W, a, h, pq, pt);
    if (fused) {
        alpha2_kernel<<<BB * SS, 256, 0, stream>>>(pq, pt, eidx, eattr, mask8, a, alpha);
    } else {
        alpha_kernel<<<BB * SS, 256, 0, stream>>>(h, eidx, eattr, mask8, a, alpha);
    }
    agg_kernel<<<dim3(BB * SS, 8), 256, 0, stream>>>(h, eidx, mask8, alpha, out);
}